// Round 5
// baseline (207.399 us; speedup 1.0000x reference)
//
#include <hip/hip_runtime.h>
#include <cstdint>
#include <math.h>

typedef _Float16 f16;
typedef _Float16 f16x2 __attribute__((ext_vector_type(2)));
typedef _Float16 f16x4 __attribute__((ext_vector_type(4)));
typedef _Float16 f16x8 __attribute__((ext_vector_type(8)));
typedef __fp16   h16x2 __attribute__((ext_vector_type(2)));
typedef float    f32x4 __attribute__((ext_vector_type(4)));

__device__ __forceinline__ f32x4 mfma16(f16x8 a, f16x8 b, f32x4 c) {
  return __builtin_amdgcn_mfma_f32_16x16x32_f16(a, b, c, 0, 0, 0);
}
__device__ __forceinline__ void gl2lds16(const f16* g, f16* l) {
  __builtin_amdgcn_global_load_lds((__attribute__((address_space(1))) void*)(g),
                                   (__attribute__((address_space(3))) void*)(l),
                                   16, 0, 0);
}
__device__ __forceinline__ float fexp2(float x) { return __builtin_amdgcn_exp2f(x); }
__device__ __forceinline__ f16x2 pkrtz(float a, float b) {
  h16x2 r = __builtin_amdgcn_cvt_pkrtz(a, b);
  return __builtin_bit_cast(f16x2, r);
}
__device__ __forceinline__ float dot2acc(f16x2 a, f16x2 b, float c) {
#if __has_builtin(__builtin_amdgcn_fdot2)
  return __builtin_amdgcn_fdot2(__builtin_bit_cast(h16x2, a),
                                __builtin_bit_cast(h16x2, b), c, false);
#else
  return c + (float)a[0] * (float)b[0] + (float)a[1] * (float)b[1];
#endif
}

// ---------------- fp32 -> f16 conversion ----------------
__global__ __launch_bounds__(256) void cvt_kernel(
    const float* __restrict__ x,  const float* __restrict__ wq, const float* __restrict__ wk,
    const float* __restrict__ wv, const float* __restrict__ wo,
    f16* __restrict__ xh, f16* __restrict__ wqkvh, f16* __restrict__ woh)
{
  const int seg = blockIdx.y;
  const float* src; f16* dst; int n;
  if      (seg == 0) { src = x;  dst = xh;              n = 4194304; }
  else if (seg == 1) { src = wq; dst = wqkvh;           n = 1048576; }
  else if (seg == 2) { src = wk; dst = wqkvh + 1048576; n = 1048576; }
  else if (seg == 3) { src = wv; dst = wqkvh + 2097152; n = 1048576; }
  else               { src = wo; dst = woh;             n = 1048576; }
  const int idx = (int)(blockIdx.x * 256 + threadIdx.x) * 8;
  if (idx >= n) return;
  f32x4 a = *(const f32x4*)(src + idx);
  f32x4 b = *(const f32x4*)(src + idx + 4);
  f16x8 h;
  h[0] = (f16)a[0]; h[1] = (f16)a[1]; h[2] = (f16)a[2]; h[3] = (f16)a[3];
  h[4] = (f16)b[0]; h[5] = (f16)b[1]; h[6] = (f16)b[2]; h[7] = (f16)b[3];
  *(f16x8*)(dst + idx) = h;
}

// ---------------- QKV GEMM: 128x128 tile, BK=32 ----------------
__global__ __launch_bounds__(256) void gemm_qkv(
    const f16* __restrict__ A, const f16* __restrict__ B,
    const float* __restrict__ bias0, const float* __restrict__ bias1, const float* __restrict__ bias2,
    f16* __restrict__ Qp, f16* __restrict__ Kp, f16* __restrict__ Vp)
{
  constexpr int K = 1024;
  __shared__ __align__(16) f16 As[128 * 32];
  __shared__ __align__(16) f16 Bs[128 * 32];
  const int tid  = threadIdx.x;
  const int wave = tid >> 6, lane = tid & 63;
  const int quad = lane >> 4, col = lane & 15;
  const int tile_m = blockIdx.y * 128, tile_n = blockIdx.x * 128;
  const int mb = (wave >> 1) * 64, nb = (wave & 1) * 64;
  const int srow = lane >> 2, scol = (lane & 3) * 8;
  const f16* gA = A + (size_t)(tile_m + wave * 32 + srow) * K + scol;
  const f16* gB = B + (size_t)(tile_n + wave * 32 + srow) * K + scol;
  f16* lA = As + wave * 1024;
  f16* lB = Bs + wave * 1024;

  f32x4 acc[4][4] = {};
  for (int k0 = 0; k0 < K; k0 += 32) {
    gl2lds16(gA + k0,          lA);
    gl2lds16(gA + 16 * K + k0, lA + 512);
    gl2lds16(gB + k0,          lB);
    gl2lds16(gB + 16 * K + k0, lB + 512);
    __syncthreads();
    f16x8 af[4], bf[4];
    #pragma unroll
    for (int i = 0; i < 4; ++i)
      af[i] = *(const f16x8*)&As[(mb + i * 16 + col) * 32 + quad * 8];
    #pragma unroll
    for (int j = 0; j < 4; ++j)
      bf[j] = *(const f16x8*)&Bs[(nb + j * 16 + col) * 32 + quad * 8];
    #pragma unroll
    for (int i = 0; i < 4; ++i)
      #pragma unroll
      for (int j = 0; j < 4; ++j)
        acc[i][j] = mfma16(af[i], bf[j], acc[i][j]);
    __syncthreads();
  }

  #pragma unroll
  for (int j = 0; j < 4; ++j) {
    const int gn = tile_n + nb + j * 16 + col;
    const int which = gn >> 10;
    const int d = gn & 1023;
    const float* bp = (which == 0) ? bias0 : (which == 1) ? bias1 : bias2;
    f16* dst        = (which == 0) ? Qp    : (which == 1) ? Kp    : Vp;
    const float bvv = bp[d];
    const float qs  = (which == 0) ? 0.18033688f : 1.0f;  // 1/sqrt(64)*log2(e) folded into Q
    const int h = d >> 6, hi = d & 63;
    #pragma unroll
    for (int i = 0; i < 4; ++i) {
      #pragma unroll
      for (int r = 0; r < 4; ++r) {
        const int gm = tile_m + mb + i * 16 + quad * 4 + r;
        const int bb = gm >> 11, s = gm & 2047;
        dst[(((size_t)bb * 16 + h) * 2048 + s) * 64 + hi] = (f16)((acc[i][j][r] + bvv) * qs);
      }
    }
  }
}

// ---------------- V transpose: [B,H,S,64] -> [B,H,64,S] ----------------
__global__ __launch_bounds__(256) void vtrans_kernel(
    const f16* __restrict__ Vh, f16* __restrict__ Vt)
{
  __shared__ __align__(16) f16 t[64][72];
  const int bh = blockIdx.y;
  const int s0 = blockIdx.x * 64;
  const int tid = threadIdx.x;
  const int sr = tid >> 2, dc = (tid & 3) * 16;
  const size_t ib = ((size_t)bh * 2048 + s0 + sr) * 64 + dc;
  f16x8 v0 = *(const f16x8*)&Vh[ib];
  f16x8 v1 = *(const f16x8*)&Vh[ib + 8];
  *(f16x8*)&t[sr][dc]     = v0;
  *(f16x8*)&t[sr][dc + 8] = v1;
  __syncthreads();
  const int d = tid >> 2, sc = (tid & 3) * 16;
  f16x8 o0, o1;
  #pragma unroll
  for (int j = 0; j < 8; ++j) { o0[j] = t[sc + j][d]; o1[j] = t[sc + 8 + j][d]; }
  const size_t ob = ((size_t)bh * 64 + d) * 2048 + s0 + sc;
  *(f16x8*)&Vt[ob]     = o0;
  *(f16x8*)&Vt[ob + 8] = o1;
}

// ---------------- flash attention, split-kv ----------------
// R4 body (4 waves x 16q, KVBLK 64, dbuf 1-barrier, defer-max, deferred-l)
// kept byte-identical; only the WORK DECOMPOSITION changes.
// R4 post-mortem: per-CU pipes sum to ~92% (MFMA 16 + VALU 36 + LDS 40) but
// each <41% busy -> serialization; exactly 2.0 barrier-locked blocks/CU can't
// drift. Fix: split each q-tile's kv range in 2 chunks; block x handles
// chunk0 of tile x + chunk1 of tile 31-x -> grid (32,32)=1024 blocks, uniform
// 16-17 iters, 3 resident blocks/CU (LDS 46KB). Each segment emits a
// normalized partial (ctx_n f16, m/l f32); combine_kernel merges.
__global__ __launch_bounds__(256) void attn_kernel(
    const f16* __restrict__ Q, const f16* __restrict__ K, const f16* __restrict__ Vt,
    f16* __restrict__ cp0, f16* __restrict__ cp1, float* __restrict__ ml)
{
  __shared__ __align__(16) f16 Ks[2][64 * 72];   // [buf][kv][d], pad 72
  __shared__ __align__(16) f16 Vts[2][64 * 72];  // [buf][d][kv], pad 72
  __shared__ __align__(16) f16 Ps[4][16 * 72];   // per-wave P [16 q][64 kv], pad 72

  const int bh  = blockIdx.y;
  const int tid = threadIdx.x;
  const int wave = tid >> 6, lane = tid & 63;
  const int quad = lane >> 4, col = lane & 15;
  const int b = bh >> 4, h = bh & 15;
  const size_t base = (size_t)bh * 2048 * 64;
  const size_t vtb  = (size_t)bh * 64 * 2048;

  // staging map: 512 16B-chunks per tensor, 2 per thread
  int srow[2], sc8[2];
  #pragma unroll
  for (int i = 0; i < 2; ++i) {
    const int flat = tid + i * 256;
    srow[i] = flat >> 3;
    sc8[i]  = (flat & 7) * 8;
  }

  // segment: kv tiles [t0, t1) of q-tile qt -> partial into cdst + ml[chunk]
  auto run_seg = [&](int qt, int t0, int t1, f16* __restrict__ cdst, int chunk) {
    const int q0 = qt * 64;
    const int qa = q0 + wave * 16;        // this wave's 16 q rows
    float ma = -INFINITY;
    float la = 0.f;                       // quad-partial row sum

    if (t1 > t0) {
      const f16x8 bqa0 = *(const f16x8*)&Q[base + (size_t)(qa + col) * 64 + quad * 8];
      const f16x8 bqa1 = *(const f16x8*)&Q[base + (size_t)(qa + col) * 64 + 32 + quad * 8];

      f32x4 cta[4] = {};

      f16x8 kr[2], vr[2];
      auto gload = [&](int t) {
        #pragma unroll
        for (int i = 0; i < 2; ++i) {
          kr[i] = *(const f16x8*)&K[base + (size_t)(t * 64 + srow[i]) * 64 + sc8[i]];
          vr[i] = *(const f16x8*)&Vt[vtb + (size_t)srow[i] * 2048 + t * 64 + sc8[i]];
        }
      };
      auto swrite = [&](int buf) {
        #pragma unroll
        for (int i = 0; i < 2; ++i) {
          *(f16x8*)&Ks[buf][srow[i] * 72 + sc8[i]]  = kr[i];
          *(f16x8*)&Vts[buf][srow[i] * 72 + sc8[i]] = vr[i];
        }
      };

      // prologue: stage tile t0 into buf0, prefetch t0+1 into regs
      gload(t0);
      __syncthreads();                // protect Ks/Vts vs previous segment's readers
      swrite(0);
      if (t0 + 1 < t1) gload(t0 + 1);

      for (int t = t0; t < t1; ++t) {
        const int cur = (t - t0) & 1;
        __syncthreads();              // buf[cur] staged by all; own vmcnt drained
        if (t + 1 < t1) {
          swrite(cur ^ 1);            // stage next tile
          if (t + 2 < t1) gload(t + 2);
        }

        // S^T = K Q^T : lane holds S[kv=jt*16+quad*4+r][q=col]
        f32x4 sa[4];
        #pragma unroll
        for (int jt = 0; jt < 4; ++jt) {
          const int kro = (jt * 16 + col) * 72;
          const f16x8 ak0 = *(const f16x8*)&Ks[cur][kro + quad * 8];
          const f16x8 ak1 = *(const f16x8*)&Ks[cur][kro + 32 + quad * 8];
          f32x4 za = {};
          za = mfma16(ak0, bqa0, za);
          sa[jt] = mfma16(ak1, bqa1, za);
        }

        if (t == qt) {  // diagonal: causal mask (Q pre-scaled, s in log2 units)
          #pragma unroll
          for (int jt = 0; jt < 4; ++jt) {
            const int kg = t * 64 + jt * 16 + quad * 4;
            #pragma unroll
            for (int r = 0; r < 4; ++r) {
              if (kg + r > qa + col) sa[jt][r] = -1e30f;
            }
          }
        }

        // row max (cross-quad reduce: 2 shfl_xor)
        float tm = fmaxf(fmaxf(sa[0][0], sa[0][1]), fmaxf(sa[0][2], sa[0][3]));
        #pragma unroll
        for (int jt = 1; jt < 4; ++jt)
          tm = fmaxf(tm, fmaxf(fmaxf(sa[jt][0], sa[jt][1]), fmaxf(sa[jt][2], sa[jt][3])));
        tm = fmaxf(tm, __shfl_xor(tm, 16));
        tm = fmaxf(tm, __shfl_xor(tm, 32));

        // defer-max: rescale only when a row max grows >6 (exp2 domain)
        if (__any(tm > ma + 6.f)) {
          const float mnew = fmaxf(ma, tm);
          const float alpha = fexp2(ma - mnew);   // exp2(-inf)=0 on first iter
          ma = mnew;
          la *= alpha;
          f32x4 ava;
          #pragma unroll
          for (int r = 0; r < 4; ++r) ava[r] = __shfl(alpha, quad * 4 + r);
          #pragma unroll
          for (int jd = 0; jd < 4; ++jd) cta[jd] *= ava;
        }

        // P = exp2(s - ma); quad-partial row sum (no per-iter shfl reduce)
        const f16x2 one2 = {(_Float16)1.f, (_Float16)1.f};
        float rs = 0.f;
        #pragma unroll
        for (int jt = 0; jt < 4; ++jt) {
          const f16x2 a01 = pkrtz(fexp2(sa[jt][0] - ma), fexp2(sa[jt][1] - ma));
          const f16x2 a23 = pkrtz(fexp2(sa[jt][2] - ma), fexp2(sa[jt][3] - ma));
          rs = dot2acc(a01, one2, rs);
          rs = dot2acc(a23, one2, rs);
          f16x4 pw; pw[0] = a01[0]; pw[1] = a01[1]; pw[2] = a23[0]; pw[3] = a23[1];
          *(f16x4*)&Ps[wave][col * 72 + jt * 16 + quad * 4] = pw;
        }
        la += rs;

        __asm__ volatile("s_waitcnt lgkmcnt(0)" ::: "memory");  // in-wave P RAW drain

        // ctx += P V
        const f16x8 apa0 = *(const f16x8*)&Ps[wave][col * 72 + quad * 8];
        const f16x8 apa1 = *(const f16x8*)&Ps[wave][col * 72 + 32 + quad * 8];
        #pragma unroll
        for (int jd = 0; jd < 4; ++jd) {
          const int vro = (jd * 16 + col) * 72;
          const f16x8 bv0 = *(const f16x8*)&Vts[cur][vro + quad * 8];
          const f16x8 bv1 = *(const f16x8*)&Vts[cur][vro + 32 + quad * 8];
          cta[jd] = mfma16(apa1, bv1, mfma16(apa0, bv0, cta[jd]));
        }
      }

      // segment epilogue: complete la reduction, normalize, store partial ctx
      la += __shfl_xor(la, 16);
      la += __shfl_xor(la, 32);
      f32x4 lva;
      #pragma unroll
      for (int r = 0; r < 4; ++r) lva[r] = __shfl(la, quad * 4 + r);
      #pragma unroll
      for (int jd = 0; jd < 4; ++jd) {
        #pragma unroll
        for (int r = 0; r < 4; ++r) {
          const int qga = qa + quad * 4 + r;
          const int d = h * 64 + jd * 16 + col;
          cdst[((size_t)b * 2048 + qga) * 1024 + d] = (f16)(cta[jd][r] / lva[r]);
        }
      }
    } else {
      // empty segment: la stays 0; reduce for uniformity
      la += __shfl_xor(la, 16);
      la += __shfl_xor(la, 32);
    }

    // m/l store: lane (quad==0, col) owns q = qa+col
    if (quad == 0) {
      const int row = bh * 2048 + qa + col;
      ml[chunk * 131072 + row]         = ma;   // m
      ml[chunk * 131072 + 65536 + row] = la;   // l
    }
  };

  // block x: chunk0 of tile x  +  chunk1 of tile 31-x  (16-17 iters uniform)
  const int x = blockIdx.x;
  const int qa_t = x;                  // segment A tile
  const int a1 = (x + 2) >> 1;         // ceil((x+1)/2)
  const int qb_t = 31 - x;             // segment B tile
  const int nb_ = 32 - x;              // its total kv tiles
  const int b0 = (nb_ + 1) >> 1;       // chunk1 start = ceil(nb/2)

  run_seg(qa_t, 0, a1, cp0, 0);
  run_seg(qb_t, b0, nb_, cp1, 1);
}

// ---------------- split-kv combine ----------------
// out = (c0*l0*w0 + c1*l1*w1) / (l0*w0 + l1*w1),  w = exp2(m - max(m0,m1))
__global__ __launch_bounds__(256) void combine_kernel(
    const f16* __restrict__ c0, const f16* __restrict__ c1,
    const float* __restrict__ ml, f16* __restrict__ out)
{
  const int gtid = (int)(blockIdx.x * 256 + threadIdx.x);  // 524288: (row, d8)
  const int d0 = (gtid & 7) * 8;
  const int row = gtid >> 3;            // bh*2048 + q
  const int bh = row >> 11, q = row & 2047;
  const int b = bh >> 4, h = bh & 15;
  const float m0 = ml[row],          l0 = ml[65536 + row];
  const float m1 = ml[131072 + row], l1 = ml[196608 + row];
  const float M = fmaxf(m0, m1);
  const float s0 = l0 * fexp2(m0 - M);
  const float s1 = l1 * fexp2(m1 - M);
  const size_t idx = ((size_t)b * 2048 + q) * 1024 + h * 64 + d0;
  f16x8 v0 = *(const f16x8*)&c0[idx];
  f16x8 r;
  if (s1 > 0.f) {
    const float inv = 1.f / (s0 + s1);
    f16x8 v1 = *(const f16x8*)&c1[idx];
    #pragma unroll
    for (int i = 0; i < 8; ++i)
      r[i] = (f16)(((float)v0[i] * s0 + (float)v1[i] * s1) * inv);
  } else {
    r = v0;   // s0/(s0+0) == 1
  }
  *(f16x8*)&out[idx] = r;
}

// ---------------- O projection: 128x64 tile, BK=32 ----------------
__global__ __launch_bounds__(256) void gemm_o(
    const f16* __restrict__ A, const f16* __restrict__ B, const float* __restrict__ bias,
    float* __restrict__ Out)
{
  constexpr int K = 1024;
  __shared__ __align__(16) f16 As[128 * 32];
  __shared__ __align__(16) f16 Bs[64 * 32];
  const int tid  = threadIdx.x;
  const int wave = tid >> 6, lane = tid & 63;
  const int quad = lane >> 4, col = lane & 15;
  const int tile_m = blockIdx.y * 128, tile_n = blockIdx.x * 64;
  const int mb = wave * 32;
  const int srow = lane >> 2, scol = (lane & 3) * 8;
  const f16* gA = A + (size_t)(tile_m + wave * 32 + srow) * K + scol;
  const f16* gB = B + (size_t)(tile_n + wave * 16 + srow) * K + scol;
  f16* lA = As + wave * 1024;
  f16* lB = Bs + wave * 512;

  f32x4 acc[2][4] = {};
  for (int k0 = 0; k0 < K; k0 += 32) {
    gl2lds16(gA + k0,          lA);
    gl2lds16(gA + 16 * K + k0, lA + 512);
    gl2lds16(gB + k0,          lB);
    __syncthreads();
    f16x8 af[2], bf[4];
    #pragma unroll
    for (int i = 0; i < 2; ++i)
      af[i] = *(const f16x8*)&As[(mb + i * 16 + col) * 32 + quad * 8];
    #pragma unroll
    for (int j = 0; j < 4; ++j)
      bf[j] = *(const f16x8*)&Bs[(j * 16 + col) * 32 + quad * 8];
    #pragma unroll
    for (int i = 0; i < 2; ++i)
      #pragma unroll
      for (int j = 0; j < 4; ++j)
        acc[i][j] = mfma16(af[i], bf[j], acc[i][j]);
    __syncthreads();
  }

  #pragma unroll
  for (int j = 0; j < 4; ++j) {
    const int gn = tile_n + j * 16 + col;
    const float bvv = bias[gn];
    #pragma unroll
    for (int i = 0; i < 2; ++i) {
      #pragma unroll
      for (int r = 0; r < 4; ++r) {
        const int gm = tile_m + mb + i * 16 + quad * 4 + r;
        Out[(size_t)gm * 1024 + gn] = acc[i][j][r] + bvv;
      }
    }
  }
}

extern "C" void kernel_launch(void* const* d_in, const int* in_sizes, int n_in,
                              void* d_out, int out_size, void* d_ws, size_t ws_size,
                              hipStream_t stream)
{
  const float* x  = (const float*)d_in[0];
  const float* Wq = (const float*)d_in[1];
  const float* bq = (const float*)d_in[2];
  const float* Wk = (const float*)d_in[3];
  const float* bk = (const float*)d_in[4];
  const float* Wv = (const float*)d_in[5];
  const float* bv = (const float*)d_in[6];
  const float* Wo = (const float*)d_in[7];
  const float* bo = (const float*)d_in[8];
  float* out = (float*)d_out;

  f16* ws = (f16*)d_ws;
  const size_t M1 = 1048576;
  f16* xh    = ws;             // 4M halves  (dead after gemm_qkv -> reused as cp0)
  f16* wqkvh = ws + 4  * M1;   // 3M         (dead after gemm_qkv -> reused as ml)
  f16* woh   = ws + 7  * M1;   // 1M  (live until gemm_o)
  f16* Qh    = ws + 8  * M1;   // 4M  [B,H,S,64] (pre-scaled)
  f16* Kh    = ws + 12 * M1;   // 4M  [B,H,S,64]
  f16* Vh    = ws + 16 * M1;   // 4M  [B,H,S,64] (dead after vtrans -> reused as cp1)
  f16* Vth   = ws + 20 * M1;   // 4M  [B,H,64,S]
  f16* ctxh  = ws + 24 * M1;   // 4M  [B,S,D]

  f16*   cp0 = xh;                       // partial ctx chunk0 [B,S,D]
  f16*   cp1 = Vh;                       // partial ctx chunk1 [B,S,D]
  float* ml  = (float*)wqkvh;            // [2][m|l][65536] f32 = 1MB

  cvt_kernel<<<dim3(2048, 5), 256, 0, stream>>>(x, Wq, Wk, Wv, Wo, xh, wqkvh, woh);
  gemm_qkv<<<dim3(24, 32), 256, 0, stream>>>(xh, wqkvh, bq, bk, bv, Qh, Kh, Vh);
  vtrans_kernel<<<dim3(32, 32), 256, 0, stream>>>(Vh, Vth);
  attn_kernel<<<dim3(32, 32), 256, 0, stream>>>(Qh, Kh, Vth, cp0, cp1, ml);
  combine_kernel<<<2048, 256, 0, stream>>>(cp0, cp1, ml, ctxh);
  gemm_o<<<dim3(16, 32), 256, 0, stream>>>(ctxh, woh, bo, out);
}

// Round 6
// 191.635 us; speedup vs baseline: 1.0823x; 1.0823x over previous
//
#include <hip/hip_runtime.h>
#include <cstdint>
#include <math.h>

typedef _Float16 f16;
typedef _Float16 f16x2 __attribute__((ext_vector_type(2)));
typedef _Float16 f16x4 __attribute__((ext_vector_type(4)));
typedef _Float16 f16x8 __attribute__((ext_vector_type(8)));
typedef __fp16   h16x2 __attribute__((ext_vector_type(2)));
typedef float    f32x4 __attribute__((ext_vector_type(4)));

__device__ __forceinline__ f32x4 mfma16(f16x8 a, f16x8 b, f32x4 c) {
  return __builtin_amdgcn_mfma_f32_16x16x32_f16(a, b, c, 0, 0, 0);
}
__device__ __forceinline__ void gl2lds16(const f16* g, f16* l) {
  __builtin_amdgcn_global_load_lds((__attribute__((address_space(1))) void*)(g),
                                   (__attribute__((address_space(3))) void*)(l),
                                   16, 0, 0);
}
__device__ __forceinline__ float fexp2(float x) { return __builtin_amdgcn_exp2f(x); }
__device__ __forceinline__ f16x2 pkrtz(float a, float b) {
  h16x2 r = __builtin_amdgcn_cvt_pkrtz(a, b);
  return __builtin_bit_cast(f16x2, r);
}
__device__ __forceinline__ float dot2acc(f16x2 a, f16x2 b, float c) {
#if __has_builtin(__builtin_amdgcn_fdot2)
  return __builtin_amdgcn_fdot2(__builtin_bit_cast(h16x2, a),
                                __builtin_bit_cast(h16x2, b), c, false);
#else
  return c + (float)a[0] * (float)b[0] + (float)a[1] * (float)b[1];
#endif
}

// ---------------- fp32 -> f16 conversion ----------------
__global__ __launch_bounds__(256) void cvt_kernel(
    const float* __restrict__ x,  const float* __restrict__ wq, const float* __restrict__ wk,
    const float* __restrict__ wv, const float* __restrict__ wo,
    f16* __restrict__ xh, f16* __restrict__ wqkvh, f16* __restrict__ woh)
{
  const int seg = blockIdx.y;
  const float* src; f16* dst; int n;
  if      (seg == 0) { src = x;  dst = xh;              n = 4194304; }
  else if (seg == 1) { src = wq; dst = wqkvh;           n = 1048576; }
  else if (seg == 2) { src = wk; dst = wqkvh + 1048576; n = 1048576; }
  else if (seg == 3) { src = wv; dst = wqkvh + 2097152; n = 1048576; }
  else               { src = wo; dst = woh;             n = 1048576; }
  const int idx = (int)(blockIdx.x * 256 + threadIdx.x) * 8;
  if (idx >= n) return;
  f32x4 a = *(const f32x4*)(src + idx);
  f32x4 b = *(const f32x4*)(src + idx + 4);
  f16x8 h;
  h[0] = (f16)a[0]; h[1] = (f16)a[1]; h[2] = (f16)a[2]; h[3] = (f16)a[3];
  h[4] = (f16)b[0]; h[5] = (f16)b[1]; h[6] = (f16)b[2]; h[7] = (f16)b[3];
  *(f16x8*)(dst + idx) = h;
}

// ---------------- QKV GEMM: 128x128 tile, BK=32 ----------------
__global__ __launch_bounds__(256) void gemm_qkv(
    const f16* __restrict__ A, const f16* __restrict__ B,
    const float* __restrict__ bias0, const float* __restrict__ bias1, const float* __restrict__ bias2,
    f16* __restrict__ Qp, f16* __restrict__ Kp, f16* __restrict__ Vp)
{
  constexpr int K = 1024;
  __shared__ __align__(16) f16 As[128 * 32];
  __shared__ __align__(16) f16 Bs[128 * 32];
  const int tid  = threadIdx.x;
  const int wave = tid >> 6, lane = tid & 63;
  const int quad = lane >> 4, col = lane & 15;
  const int tile_m = blockIdx.y * 128, tile_n = blockIdx.x * 128;
  const int mb = (wave >> 1) * 64, nb = (wave & 1) * 64;
  const int srow = lane >> 2, scol = (lane & 3) * 8;
  const f16* gA = A + (size_t)(tile_m + wave * 32 + srow) * K + scol;
  const f16* gB = B + (size_t)(tile_n + wave * 32 + srow) * K + scol;
  f16* lA = As + wave * 1024;
  f16* lB = Bs + wave * 1024;

  f32x4 acc[4][4] = {};
  for (int k0 = 0; k0 < K; k0 += 32) {
    gl2lds16(gA + k0,          lA);
    gl2lds16(gA + 16 * K + k0, lA + 512);
    gl2lds16(gB + k0,          lB);
    gl2lds16(gB + 16 * K + k0, lB + 512);
    __syncthreads();
    f16x8 af[4], bf[4];
    #pragma unroll
    for (int i = 0; i < 4; ++i)
      af[i] = *(const f16x8*)&As[(mb + i * 16 + col) * 32 + quad * 8];
    #pragma unroll
    for (int j = 0; j < 4; ++j)
      bf[j] = *(const f16x8*)&Bs[(nb + j * 16 + col) * 32 + quad * 8];
    #pragma unroll
    for (int i = 0; i < 4; ++i)
      #pragma unroll
      for (int j = 0; j < 4; ++j)
        acc[i][j] = mfma16(af[i], bf[j], acc[i][j]);
    __syncthreads();
  }

  #pragma unroll
  for (int j = 0; j < 4; ++j) {
    const int gn = tile_n + nb + j * 16 + col;
    const int which = gn >> 10;
    const int d = gn & 1023;
    const float* bp = (which == 0) ? bias0 : (which == 1) ? bias1 : bias2;
    f16* dst        = (which == 0) ? Qp    : (which == 1) ? Kp    : Vp;
    const float bvv = bp[d];
    const float qs  = (which == 0) ? 0.18033688f : 1.0f;  // 1/sqrt(64)*log2(e) folded into Q
    const int h = d >> 6, hi = d & 63;
    #pragma unroll
    for (int i = 0; i < 4; ++i) {
      #pragma unroll
      for (int r = 0; r < 4; ++r) {
        const int gm = tile_m + mb + i * 16 + quad * 4 + r;
        const int bb = gm >> 11, s = gm & 2047;
        dst[(((size_t)bb * 16 + h) * 2048 + s) * 64 + hi] = (f16)((acc[i][j][r] + bvv) * qs);
      }
    }
  }
}

// ---------------- V transpose: [B,H,S,64] -> [B,H,64,S] ----------------
__global__ __launch_bounds__(256) void vtrans_kernel(
    const f16* __restrict__ Vh, f16* __restrict__ Vt)
{
  __shared__ __align__(16) f16 t[64][72];
  const int bh = blockIdx.y;
  const int s0 = blockIdx.x * 64;
  const int tid = threadIdx.x;
  const int sr = tid >> 2, dc = (tid & 3) * 16;
  const size_t ib = ((size_t)bh * 2048 + s0 + sr) * 64 + dc;
  f16x8 v0 = *(const f16x8*)&Vh[ib];
  f16x8 v1 = *(const f16x8*)&Vh[ib + 8];
  *(f16x8*)&t[sr][dc]     = v0;
  *(f16x8*)&t[sr][dc + 8] = v1;
  __syncthreads();
  const int d = tid >> 2, sc = (tid & 3) * 16;
  f16x8 o0, o1;
  #pragma unroll
  for (int j = 0; j < 8; ++j) { o0[j] = t[sc + j][d]; o1[j] = t[sc + 8 + j][d]; }
  const size_t ob = ((size_t)bh * 64 + d) * 2048 + s0 + sc;
  *(f16x8*)&Vt[ob]     = o0;
  *(f16x8*)&Vt[ob + 8] = o1;
}

// ---------------- flash attention ----------------
// R4 body exactly (4 waves x 16q, KVBLK 64, dbuf 1-barrier, defer-max,
// deferred-l). R5 split-kv reverted (regressed: 2x prologue/epilogue + 2x
// write traffic, occupancy up but dur up).
// NEW vs R4: grid transposed to (32,16) with x=bh, y=pair. Dispatch flat id
// = pair*32 + bh -> XCD ~ flat%8 = bh%8, so all 16 pair-blocks sharing one
// bh's K/V land on ONE XCD's L2 (4 bh x ~1MB = 4MB working set/XCD).
// R4's (16,32) gave XCD = pair%8: K/V fetched by all 8 XCDs -> FETCH_SIZE
// 120MB vs ~24MB compulsory, and gload prefetches missed L2 (~900cy) on the
// barrier-locked chain.
__global__ __launch_bounds__(256) void attn_kernel(
    const f16* __restrict__ Q, const f16* __restrict__ K, const f16* __restrict__ Vt,
    f16* __restrict__ ctx)
{
  __shared__ __align__(16) f16 Ks[2][64 * 72];   // [buf][kv][d], pad 72
  __shared__ __align__(16) f16 Vts[2][64 * 72];  // [buf][d][kv], pad 72
  __shared__ __align__(16) f16 Ps[4][16 * 72];   // per-wave P [16 q][64 kv], pad 72

  const int bh  = blockIdx.x;                    // x = bh: same-bh blocks -> same XCD
  const int tid = threadIdx.x;
  const int wave = tid >> 6, lane = tid & 63;
  const int quad = lane >> 4, col = lane & 15;
  const int b = bh >> 4, h = bh & 15;
  const size_t base = (size_t)bh * 2048 * 64;
  const size_t vtb  = (size_t)bh * 64 * 2048;

  // staging map: 512 16B-chunks per tensor, 2 per thread
  int srow[2], sc8[2];
  #pragma unroll
  for (int i = 0; i < 2; ++i) {
    const int flat = tid + i * 256;
    srow[i] = flat >> 3;
    sc8[i]  = (flat & 7) * 8;
  }

  auto run_tile = [&](int qt) {
    const int q0 = qt * 64;
    const int qa = q0 + wave * 16;        // this wave's 16 q rows
    const f16x8 bqa0 = *(const f16x8*)&Q[base + (size_t)(qa + col) * 64 + quad * 8];
    const f16x8 bqa1 = *(const f16x8*)&Q[base + (size_t)(qa + col) * 64 + 32 + quad * 8];

    f32x4 cta[4] = {};
    float ma = -INFINITY;
    float la = 0.f;                       // quad-partial row sum

    f16x8 kr[2], vr[2];
    auto gload = [&](int t) {
      #pragma unroll
      for (int i = 0; i < 2; ++i) {
        kr[i] = *(const f16x8*)&K[base + (size_t)(t * 64 + srow[i]) * 64 + sc8[i]];
        vr[i] = *(const f16x8*)&Vt[vtb + (size_t)srow[i] * 2048 + t * 64 + sc8[i]];
      }
    };
    auto swrite = [&](int buf) {
      #pragma unroll
      for (int i = 0; i < 2; ++i) {
        *(f16x8*)&Ks[buf][srow[i] * 72 + sc8[i]]  = kr[i];
        *(f16x8*)&Vts[buf][srow[i] * 72 + sc8[i]] = vr[i];
      }
    };

    const int nIter = qt + 1;

    // prologue: stage tile 0 into buf0, prefetch tile 1 into regs
    gload(0);
    __syncthreads();                  // protect Ks/Vts vs previous tile's readers
    swrite(0);
    if (nIter > 1) gload(1);

    for (int t = 0; t < nIter; ++t) {
      const int cur = t & 1;
      __syncthreads();                // buf[cur] staged by all; own vmcnt drained
      if (t + 1 < nIter) {
        swrite(cur ^ 1);              // stage next tile (regs from t-1/prologue)
        if (t + 2 < nIter) gload(t + 2);  // refill regs; covered until next barrier
      }

      // S^T = K Q^T : lane holds S[kv=jt*16+quad*4+r][q=col]
      f32x4 sa[4];
      #pragma unroll
      for (int jt = 0; jt < 4; ++jt) {
        const int kro = (jt * 16 + col) * 72;
        const f16x8 ak0 = *(const f16x8*)&Ks[cur][kro + quad * 8];
        const f16x8 ak1 = *(const f16x8*)&Ks[cur][kro + 32 + quad * 8];
        f32x4 za = {};
        za = mfma16(ak0, bqa0, za);
        sa[jt] = mfma16(ak1, bqa1, za);
      }

      if (t == qt) {  // diagonal: causal mask (Q pre-scaled, s already in log2 units)
        #pragma unroll
        for (int jt = 0; jt < 4; ++jt) {
          const int kg = t * 64 + jt * 16 + quad * 4;
          #pragma unroll
          for (int r = 0; r < 4; ++r) {
            if (kg + r > qa + col) sa[jt][r] = -1e30f;
          }
        }
      }

      // row max (cross-quad reduce: 2 shfl_xor)
      float tm = fmaxf(fmaxf(sa[0][0], sa[0][1]), fmaxf(sa[0][2], sa[0][3]));
      #pragma unroll
      for (int jt = 1; jt < 4; ++jt)
        tm = fmaxf(tm, fmaxf(fmaxf(sa[jt][0], sa[jt][1]), fmaxf(sa[jt][2], sa[jt][3])));
      tm = fmaxf(tm, __shfl_xor(tm, 16));
      tm = fmaxf(tm, __shfl_xor(tm, 32));

      // defer-max: rescale only if some row's max grew by >6 (exp2 domain,
      // P bounded by 2^6=64, fine in f16). First iter: ma=-inf -> taken.
      if (__any(tm > ma + 6.f)) {
        const float mnew = fmaxf(ma, tm);
        const float alpha = fexp2(ma - mnew);   // exp2(-inf)=0 on first iter
        ma = mnew;
        la *= alpha;
        f32x4 ava;
        #pragma unroll
        for (int r = 0; r < 4; ++r) ava[r] = __shfl(alpha, quad * 4 + r);
        #pragma unroll
        for (int jd = 0; jd < 4; ++jd) cta[jd] *= ava;
      }

      // P = exp2(s - ma); quad-partial row sum into la (no per-iter shfl reduce)
      const f16x2 one2 = {(_Float16)1.f, (_Float16)1.f};
      float rs = 0.f;
      #pragma unroll
      for (int jt = 0; jt < 4; ++jt) {
        const f16x2 a01 = pkrtz(fexp2(sa[jt][0] - ma), fexp2(sa[jt][1] - ma));
        const f16x2 a23 = pkrtz(fexp2(sa[jt][2] - ma), fexp2(sa[jt][3] - ma));
        rs = dot2acc(a01, one2, rs);
        rs = dot2acc(a23, one2, rs);
        f16x4 pw; pw[0] = a01[0]; pw[1] = a01[1]; pw[2] = a23[0]; pw[3] = a23[1];
        *(f16x4*)&Ps[wave][col * 72 + jt * 16 + quad * 4] = pw;
      }
      la += rs;

      __asm__ volatile("s_waitcnt lgkmcnt(0)" ::: "memory");  // in-wave P RAW drain

      // ctx += P V
      const f16x8 apa0 = *(const f16x8*)&Ps[wave][col * 72 + quad * 8];
      const f16x8 apa1 = *(const f16x8*)&Ps[wave][col * 72 + 32 + quad * 8];
      #pragma unroll
      for (int jd = 0; jd < 4; ++jd) {
        const int vro = (jd * 16 + col) * 72;
        const f16x8 bv0 = *(const f16x8*)&Vts[cur][vro + quad * 8];
        const f16x8 bv1 = *(const f16x8*)&Vts[cur][vro + 32 + quad * 8];
        cta[jd] = mfma16(apa1, bv1, mfma16(apa0, bv0, cta[jd]));
      }
    }

    // epilogue: complete la reduction (deferred from loop), broadcast, store
    la += __shfl_xor(la, 16);
    la += __shfl_xor(la, 32);
    f32x4 lva;
    #pragma unroll
    for (int r = 0; r < 4; ++r) lva[r] = __shfl(la, quad * 4 + r);
    #pragma unroll
    for (int jd = 0; jd < 4; ++jd) {
      #pragma unroll
      for (int r = 0; r < 4; ++r) {
        const int qga = qa + quad * 4 + r;
        const int d = h * 64 + jd * 16 + col;
        ctx[((size_t)b * 2048 + qga) * 1024 + d] = (f16)(cta[jd][r] / lva[r]);
      }
    }
  };

  run_tile(blockIdx.y);        // tiles 0..15
  run_tile(31 - blockIdx.y);   // tiles 31..16  -> uniform 33 kv-iters per block
}

// ---------------- O projection: 128x64 tile, BK=32 ----------------
__global__ __launch_bounds__(256) void gemm_o(
    const f16* __restrict__ A, const f16* __restrict__ B, const float* __restrict__ bias,
    float* __restrict__ Out)
{
  constexpr int K = 1024;
  __shared__ __align__(16) f16 As[128 * 32];
  __shared__ __align__(16) f16 Bs[64 * 32];
  const int tid  = threadIdx.x;
  const int wave = tid >> 6, lane = tid & 63;
  const int quad = lane >> 4, col = lane & 15;
  const int tile_m = blockIdx.y * 128, tile_n = blockIdx.x * 64;
  const int mb = wave * 32;
  const int srow = lane >> 2, scol = (lane & 3) * 8;
  const f16* gA = A + (size_t)(tile_m + wave * 32 + srow) * K + scol;
  const f16* gB = B + (size_t)(tile_n + wave * 16 + srow) * K + scol;
  f16* lA = As + wave * 1024;
  f16* lB = Bs + wave * 512;

  f32x4 acc[2][4] = {};
  for (int k0 = 0; k0 < K; k0 += 32) {
    gl2lds16(gA + k0,          lA);
    gl2lds16(gA + 16 * K + k0, lA + 512);
    gl2lds16(gB + k0,          lB);
    __syncthreads();
    f16x8 af[2], bf[4];
    #pragma unroll
    for (int i = 0; i < 2; ++i)
      af[i] = *(const f16x8*)&As[(mb + i * 16 + col) * 32 + quad * 8];
    #pragma unroll
    for (int j = 0; j < 4; ++j)
      bf[j] = *(const f16x8*)&Bs[(j * 16 + col) * 32 + quad * 8];
    #pragma unroll
    for (int i = 0; i < 2; ++i)
      #pragma unroll
      for (int j = 0; j < 4; ++j)
        acc[i][j] = mfma16(af[i], bf[j], acc[i][j]);
    __syncthreads();
  }

  #pragma unroll
  for (int j = 0; j < 4; ++j) {
    const int gn = tile_n + j * 16 + col;
    const float bvv = bias[gn];
    #pragma unroll
    for (int i = 0; i < 2; ++i) {
      #pragma unroll
      for (int r = 0; r < 4; ++r) {
        const int gm = tile_m + mb + i * 16 + quad * 4 + r;
        Out[(size_t)gm * 1024 + gn] = acc[i][j][r] + bvv;
      }
    }
  }
}

extern "C" void kernel_launch(void* const* d_in, const int* in_sizes, int n_in,
                              void* d_out, int out_size, void* d_ws, size_t ws_size,
                              hipStream_t stream)
{
  const float* x  = (const float*)d_in[0];
  const float* Wq = (const float*)d_in[1];
  const float* bq = (const float*)d_in[2];
  const float* Wk = (const float*)d_in[3];
  const float* bk = (const float*)d_in[4];
  const float* Wv = (const float*)d_in[5];
  const float* bv = (const float*)d_in[6];
  const float* Wo = (const float*)d_in[7];
  const float* bo = (const float*)d_in[8];
  float* out = (float*)d_out;

  f16* ws = (f16*)d_ws;
  const size_t M1 = 1048576;
  f16* xh    = ws;             // 4M halves
  f16* wqkvh = ws + 4  * M1;   // 3M
  f16* woh   = ws + 7  * M1;   // 1M
  f16* Qh    = ws + 8  * M1;   // 4M  [B,H,S,64] (pre-scaled)
  f16* Kh    = ws + 12 * M1;   // 4M  [B,H,S,64]
  f16* Vh    = ws + 16 * M1;   // 4M  [B,H,S,64]
  f16* Vth   = ws + 20 * M1;   // 4M  [B,H,64,S]
  f16* ctxh  = ws + 24 * M1;   // 4M  [B,S,D]

  cvt_kernel<<<dim3(2048, 5), 256, 0, stream>>>(x, Wq, Wk, Wv, Wo, xh, wqkvh, woh);
  gemm_qkv<<<dim3(24, 32), 256, 0, stream>>>(xh, wqkvh, bq, bk, bv, Qh, Kh, Vh);
  vtrans_kernel<<<dim3(32, 32), 256, 0, stream>>>(Vh, Vth);
  attn_kernel<<<dim3(32, 16), 256, 0, stream>>>(Qh, Kh, Vth, ctxh);
  gemm_o<<<dim3(16, 32), 256, 0, stream>>>(ctxh, woh, bo, out);
}